// Round 2
// baseline (726.712 us; speedup 1.0000x reference)
//
#include <hip/hip_runtime.h>
#include <math.h>

#define B_TOTAL 65536
#define IN_DIM 512
#define HID_DIM 512
#define FAN1 1024
#define NQ 8
#define NGATES 4

__device__ __forceinline__ float sigmoid_f(float v) {
    return 1.0f / (1.0f + __expf(-v));
}
__device__ __forceinline__ float tanh_fast(float v) {
    // 1 - 2/(e^{2v}+1); saturates correctly for |v| large.
    return 1.0f - 2.0f / (__expf(2.0f * v) + 1.0f);
}

// ---------------------------------------------------------------------------
// Fused LSTM cell: one block = 64 batch rows, 256 threads (4 waves).
// Phase 1: z = tanh(combined @ W1^T + b1)  -> LDS  (wave g computes gate g)
//   - combined AND W1 chunk staged in LDS (W1 via broadcast ds_reads: no
//     scalar-load latency stalls like the previous kernel).
//   - next chunk global loads issued into registers BEFORE compute of the
//     current chunk (issue-early / write-late): HBM latency hides under FMAs.
// Phase 2: gates = sigmoid(z @ W2 + b2); LSTM elementwise.
//   - thread owns 2 adjacent hid columns -> float2 c loads / float2 stores.
//   - W2 slice (64 floats) in VGPRs, amortized over 64 rows.
//   - depth-2 row pipeline on the c loads (covers ~900 cy HBM latency).
// ---------------------------------------------------------------------------
__global__ __launch_bounds__(256, 4)
void lstm_fused(const float* __restrict__ x, const float* __restrict__ h,
                const float* __restrict__ c,
                const float* __restrict__ W1, const float* __restrict__ b1,
                const float* __restrict__ W2, const float* __restrict__ b2,
                float* __restrict__ out) {
    __shared__ __align__(16) float tile[64][64];  // 16 KB combined chunk (XOR swizzled)
    __shared__ __align__(16) float w1s[32][64];   //  8 KB W1 chunk
    __shared__ __align__(16) float zs[64][36];    //  9 KB z, stride-36 pad -> conflict-free

    const int tid  = threadIdx.x;
    const int lane = tid & 63;
    const int g    = __builtin_amdgcn_readfirstlane(tid >> 6);  // wave id == gate
    const int rowbase = blockIdx.x * 64;

    const int srow = tid >> 4;   // staging row base 0..15
    const int skg  = tid & 15;   // staging float4-group 0..15

    float acc[8];
#pragma unroll
    for (int j = 0; j < 8; ++j) acc[j] = 0.0f;

    float4 tReg[4];
    float4 wReg[2];

    // ---- prologue: issue global loads for chunk 0 ----
    {
        const float* src = x;  // kc = 0 < IN_DIM
#pragma unroll
        for (int i = 0; i < 4; ++i) {
            int r = srow + 16 * i;
            tReg[i] = *(const float4*)(src + (size_t)(rowbase + r) * 512 + skg * 4);
        }
#pragma unroll
        for (int i = 0; i < 2; ++i) {
            int o = srow + 16 * i;
            wReg[i] = *(const float4*)(W1 + (size_t)o * FAN1 + skg * 4);
        }
    }

    // ---- phase 1 main loop over 16 K-chunks of 64 ----
    for (int kc = 0; kc < FAN1; kc += 64) {
        __syncthreads();  // protect tile against readers of previous chunk
        // write staged registers -> LDS
#pragma unroll
        for (int i = 0; i < 4; ++i) {
            int r = srow + 16 * i;
            *(float4*)&tile[r][(skg ^ (r & 7)) << 2] = tReg[i];
        }
#pragma unroll
        for (int i = 0; i < 2; ++i) {
            int o = srow + 16 * i;
            *(float4*)&w1s[o][skg << 2] = wReg[i];
        }
        __syncthreads();

        // prefetch next chunk into registers (in flight across the compute)
        const int kn = kc + 64;
        if (kn < FAN1) {
            const float* src = (kn < IN_DIM) ? (x + kn) : (h + (kn - IN_DIM));
#pragma unroll
            for (int i = 0; i < 4; ++i) {
                int r = srow + 16 * i;
                tReg[i] = *(const float4*)(src + (size_t)(rowbase + r) * 512 + skg * 4);
            }
#pragma unroll
            for (int i = 0; i < 2; ++i) {
                int o = srow + 16 * i;
                wReg[i] = *(const float4*)(W1 + (size_t)o * FAN1 + kn + skg * 4);
            }
        }

        // compute: lane owns one row; 8 outputs of gate g
#pragma unroll
        for (int kg = 0; kg < 16; ++kg) {
            float4 cv = *(const float4*)&tile[lane][(kg ^ (lane & 7)) << 2];
#pragma unroll
            for (int j = 0; j < 8; ++j) {
                // uniform address -> LDS broadcast read, conflict-free
                float4 wv = *(const float4*)&w1s[g * 8 + j][kg << 2];
                acc[j] = fmaf(cv.x, wv.x, acc[j]);
                acc[j] = fmaf(cv.y, wv.y, acc[j]);
                acc[j] = fmaf(cv.z, wv.z, acc[j]);
                acc[j] = fmaf(cv.w, wv.w, acc[j]);
            }
        }
    }

    // ---- z epilogue: bias + tanh -> LDS ----
    {
        const float* bp = b1 + g * 8;
        float t0 = tanhf(acc[0] + bp[0]);
        float t1 = tanhf(acc[1] + bp[1]);
        float t2 = tanhf(acc[2] + bp[2]);
        float t3 = tanhf(acc[3] + bp[3]);
        float t4 = tanhf(acc[4] + bp[4]);
        float t5 = tanhf(acc[5] + bp[5]);
        float t6 = tanhf(acc[6] + bp[6]);
        float t7 = tanhf(acc[7] + bp[7]);
        *(float4*)&zs[lane][g * 8 + 0] = make_float4(t0, t1, t2, t3);
        *(float4*)&zs[lane][g * 8 + 4] = make_float4(t4, t5, t6, t7);
    }

    // ---- phase-2 weight preload (issues while zs writes drain) ----
    const int hh = tid * 2;  // owns hid columns hh, hh+1
    float w2r[4][16];        // [gate][col*8 + q]
    float b2r[4][2];
#pragma unroll
    for (int g2 = 0; g2 < 4; ++g2) {
        const float* wp = W2 + ((size_t)g2 * HID_DIM + hh) * NQ;
        float4 p0 = *(const float4*)(wp + 0);
        float4 p1 = *(const float4*)(wp + 4);
        float4 p2 = *(const float4*)(wp + 8);
        float4 p3 = *(const float4*)(wp + 12);
        w2r[g2][0]  = p0.x; w2r[g2][1]  = p0.y; w2r[g2][2]  = p0.z; w2r[g2][3]  = p0.w;
        w2r[g2][4]  = p1.x; w2r[g2][5]  = p1.y; w2r[g2][6]  = p1.z; w2r[g2][7]  = p1.w;
        w2r[g2][8]  = p2.x; w2r[g2][9]  = p2.y; w2r[g2][10] = p2.z; w2r[g2][11] = p2.w;
        w2r[g2][12] = p3.x; w2r[g2][13] = p3.y; w2r[g2][14] = p3.z; w2r[g2][15] = p3.w;
        float2 bb = *(const float2*)(b2 + (size_t)g2 * HID_DIM + hh);
        b2r[g2][0] = bb.x; b2r[g2][1] = bb.y;
    }

    __syncthreads();  // zs visible to all waves

    // ---- phase 2: gates + LSTM elementwise, depth-2 c pipeline ----
    const size_t c_off = (size_t)B_TOTAL * HID_DIM;
    const float* crow = c   + (size_t)rowbase * HID_DIM + hh;
    float*       orow = out + (size_t)rowbase * HID_DIM + hh;

    float2 cA = *(const float2*)(crow);
    float2 cB = *(const float2*)(crow + HID_DIM);

#pragma unroll 1
    for (int r = 0; r < 64; r += 2) {
        float2 cN0 = cA, cN1 = cB;
        if (r + 2 < 64) {
            cN0 = *(const float2*)(crow + (size_t)(r + 2) * HID_DIM);
            cN1 = *(const float2*)(crow + (size_t)(r + 3) * HID_DIM);
        }
#pragma unroll
        for (int rr = 0; rr < 2; ++rr) {
            const int row = r + rr;
            const float2 cv = rr ? cB : cA;   // static after unroll
            const float* zr = &zs[row][0];
            float pre0[4], pre1[4];
#pragma unroll
            for (int g2 = 0; g2 < 4; ++g2) {
                float4 za = *(const float4*)(zr + g2 * 8);      // uniform -> broadcast
                float4 zb = *(const float4*)(zr + g2 * 8 + 4);
                float a0 = b2r[g2][0], a1 = b2r[g2][1];
                a0 = fmaf(za.x, w2r[g2][0], a0);
                a0 = fmaf(za.y, w2r[g2][1], a0);
                a0 = fmaf(za.z, w2r[g2][2], a0);
                a0 = fmaf(za.w, w2r[g2][3], a0);
                a0 = fmaf(zb.x, w2r[g2][4], a0);
                a0 = fmaf(zb.y, w2r[g2][5], a0);
                a0 = fmaf(zb.z, w2r[g2][6], a0);
                a0 = fmaf(zb.w, w2r[g2][7], a0);
                a1 = fmaf(za.x, w2r[g2][8], a1);
                a1 = fmaf(za.y, w2r[g2][9], a1);
                a1 = fmaf(za.z, w2r[g2][10], a1);
                a1 = fmaf(za.w, w2r[g2][11], a1);
                a1 = fmaf(zb.x, w2r[g2][12], a1);
                a1 = fmaf(zb.y, w2r[g2][13], a1);
                a1 = fmaf(zb.z, w2r[g2][14], a1);
                a1 = fmaf(zb.w, w2r[g2][15], a1);
                pre0[g2] = a0; pre1[g2] = a1;
            }
            float ig0 = sigmoid_f(pre0[0]);
            float fg0 = sigmoid_f(pre0[1]);
            float og0 = sigmoid_f(pre0[2]);
            float gg0 = sigmoid_f(pre0[3]);
            float ig1 = sigmoid_f(pre1[0]);
            float fg1 = sigmoid_f(pre1[1]);
            float og1 = sigmoid_f(pre1[2]);
            float gg1 = sigmoid_f(pre1[3]);
            float cn0 = fg0 * cv.x + ig0 * gg0;
            float cn1 = fg1 * cv.y + ig1 * gg1;
            float hn0 = og0 * tanh_fast(cn0);
            float hn1 = og1 * tanh_fast(cn1);
            size_t ob = (size_t)row * HID_DIM;
            *(float2*)(orow + ob)         = make_float2(hn0, hn1);
            *(float2*)(orow + c_off + ob) = make_float2(cn0, cn1);
        }
        cA = cN0; cB = cN1;
    }
}

extern "C" void kernel_launch(void* const* d_in, const int* in_sizes, int n_in,
                              void* d_out, int out_size, void* d_ws, size_t ws_size,
                              hipStream_t stream) {
    const float* x  = (const float*)d_in[0];
    const float* h  = (const float*)d_in[1];
    const float* c  = (const float*)d_in[2];
    const float* W1 = (const float*)d_in[3];
    const float* b1 = (const float*)d_in[4];
    const float* W2 = (const float*)d_in[5];
    const float* b2 = (const float*)d_in[6];
    float* out = (float*)d_out;

    hipLaunchKernelGGL(lstm_fused, dim3(B_TOTAL / 64), dim3(256), 0, stream,
                       x, h, c, W1, b1, W2, b2, out);
}